// Round 1
// baseline (1067.164 us; speedup 1.0000x reference)
//
#include <hip/hip_runtime.h>

// GGNN message passing, MI355X baseline (round 1: correctness-first, VALU one-hot FMA).
//   m_in[b,i,d]  = sum_{c,e} Min[c,d,e]  * s_in[b,i,c,e],  s_in  = sum_j [adj[b,i,j]==c] h[b,j,e]
//   m_out[b,i,d] = sum_{c,e} Mout[c,d,e] * s_out[b,i,c,e], s_out = sum_j [adj[b,j,i]==c] h[b,j,e]
//   out[b,i,0:64] = m_in + bias[0:64];  out[b,i,64:128] = m_out + bias[64:128]
//
// Two kernels (in / out direction), each reads adjacency once (coalesced; out
// direction transposes a [64j x 16i] tile through LDS). Block = 256 thr = 4
// waves; block owns 16 nodes of one batch; wave owns 4 nodes. Inner loop is
// branchless: f32 one-hot expanded once per chunk into LDS, then per edge
// 1 ds_read(h, lane-parallel) + 1 ds_read_b128(one-hot, broadcast) + 4 v_fma.
// Roadmap: replace accumulate with bf16 MFMA over one-hot tiles (~34 GFLOP).

namespace {

constexpr int NB = 32;
constexpr int NN = 1024;
constexpr int ND = 64;

__global__ __launch_bounds__(256) void ggnn_in(
    const float* __restrict__ h, const int* __restrict__ adj,
    const float* __restrict__ M, const float* __restrict__ bias,
    float* __restrict__ out)
{
    __shared__ float lds_h[64][64];       // h tile [j][e], 16 KB
    __shared__ float lds_oh[16][64][4];   // one-hot [row][j][class], 16 KB
    __shared__ float lds_s[16][4][64];    // epilogue staging [row][class][e], 16 KB

    const int tid  = threadIdx.x;
    const int wave = tid >> 6;
    const int lane = tid & 63;
    const int b    = blockIdx.x >> 6;          // 64 blocks per batch
    const int i0   = (blockIdx.x & 63) << 4;   // 16 rows per block

    float acc[4][4];                           // [row][class], lane = e
    #pragma unroll
    for (int r = 0; r < 4; ++r)
        #pragma unroll
        for (int c = 0; c < 4; ++c) acc[r][c] = 0.f;

    const float* hb   = h   + (size_t)b * NN * ND;
    const int*   adjb = adj + (size_t)b * NN * NN;

    for (int j0 = 0; j0 < NN; j0 += 64) {
        __syncthreads();
        // stage h[b, j0:j0+64, :] -> lds_h (coalesced float4)
        const float4* hsrc = (const float4*)(hb + j0 * ND);
        float4* hdst = (float4*)(&lds_h[0][0]);
        #pragma unroll
        for (int k = 0; k < 4; ++k) hdst[tid + 256 * k] = hsrc[tid + 256 * k];
        // one-hot expand: wave's 4 rows, lane covers column j0+lane
        #pragma unroll
        for (int r = 0; r < 4; ++r) {
            const int row = i0 + wave * 4 + r;
            const int c = adjb[(size_t)row * NN + j0 + lane];
            float4 oh;
            oh.x = (c == 0) ? 1.f : 0.f;
            oh.y = (c == 1) ? 1.f : 0.f;
            oh.z = (c == 2) ? 1.f : 0.f;
            oh.w = (c == 3) ? 1.f : 0.f;
            *(float4*)(&lds_oh[wave * 4 + r][lane][0]) = oh;
        }
        __syncthreads();
        // branchless accumulate: per edge = 4 v_fma, h read shared by 4 rows
        #pragma unroll 8
        for (int jj = 0; jj < 64; ++jj) {
            const float hv = lds_h[jj][lane];
            #pragma unroll
            for (int r = 0; r < 4; ++r) {
                const float4 oh = *(const float4*)(&lds_oh[wave * 4 + r][jj][0]);
                acc[r][0] += oh.x * hv;
                acc[r][1] += oh.y * hv;
                acc[r][2] += oh.z * hv;
                acc[r][3] += oh.w * hv;
            }
        }
    }

    // epilogue: s -> LDS transpose, then m[d] = bias[d] + sum_{c,e} M[c,d,e] s[c,e]
    #pragma unroll
    for (int r = 0; r < 4; ++r)
        #pragma unroll
        for (int c = 0; c < 4; ++c)
            lds_s[wave * 4 + r][c][lane] = acc[r][c];
    __syncthreads();

    float m[4];
    #pragma unroll
    for (int r = 0; r < 4; ++r) m[r] = bias[lane];   // lane = d
    for (int c = 0; c < 4; ++c) {
        #pragma unroll 4
        for (int e4 = 0; e4 < 16; ++e4) {
            const float4 M4 = *(const float4*)(&M[c * 4096 + lane * 64 + e4 * 4]);
            #pragma unroll
            for (int r = 0; r < 4; ++r) {
                const float4 s4 = *(const float4*)(&lds_s[wave * 4 + r][c][e4 * 4]);
                m[r] += M4.x * s4.x + M4.y * s4.y + M4.z * s4.z + M4.w * s4.w;
            }
        }
    }
    #pragma unroll
    for (int r = 0; r < 4; ++r)
        out[((size_t)b * NN + i0 + wave * 4 + r) * 128 + lane] = m[r];
}

__global__ __launch_bounds__(256) void ggnn_out(
    const float* __restrict__ h, const int* __restrict__ adj,
    const float* __restrict__ M, const float* __restrict__ bias,
    float* __restrict__ out)
{
    __shared__ float lds_h[64][64];       // h tile [j][e]
    __shared__ float lds_oh[64][16][4];   // one-hot [j][col][class] (write-coalesced layout)
    __shared__ float lds_s[16][4][64];

    const int tid  = threadIdx.x;
    const int wave = tid >> 6;
    const int lane = tid & 63;
    const int b    = blockIdx.x >> 6;
    const int i0   = (blockIdx.x & 63) << 4;   // 16 columns per block

    float acc[4][4];                           // [col][class], lane = e
    #pragma unroll
    for (int col = 0; col < 4; ++col)
        #pragma unroll
        for (int c = 0; c < 4; ++c) acc[col][c] = 0.f;

    const float* hb   = h   + (size_t)b * NN * ND;
    const int*   adjb = adj + (size_t)b * NN * NN;

    for (int j0 = 0; j0 < NN; j0 += 64) {
        __syncthreads();
        const float4* hsrc = (const float4*)(hb + j0 * ND);
        float4* hdst = (float4*)(&lds_h[0][0]);
        #pragma unroll
        for (int k = 0; k < 4; ++k) hdst[tid + 256 * k] = hsrc[tid + 256 * k];
        // transposed adjacency tile: adj[b, j0+r, i0+ci], 16 consecutive ints
        // per row -> coalesced 64B segments; write LDS in thread-linear order
        #pragma unroll
        for (int k = 0; k < 4; ++k) {
            const int idx = tid + 256 * k;
            const int r   = idx >> 4;
            const int ci  = idx & 15;
            const int c = adjb[(size_t)(j0 + r) * NN + i0 + ci];
            float4 oh;
            oh.x = (c == 0) ? 1.f : 0.f;
            oh.y = (c == 1) ? 1.f : 0.f;
            oh.z = (c == 2) ? 1.f : 0.f;
            oh.w = (c == 3) ? 1.f : 0.f;
            *(float4*)(&lds_oh[r][ci][0]) = oh;
        }
        __syncthreads();
        #pragma unroll 8
        for (int jj = 0; jj < 64; ++jj) {
            const float hv = lds_h[jj][lane];
            #pragma unroll
            for (int col = 0; col < 4; ++col) {
                const float4 oh = *(const float4*)(&lds_oh[jj][wave * 4 + col][0]);
                acc[col][0] += oh.x * hv;
                acc[col][1] += oh.y * hv;
                acc[col][2] += oh.z * hv;
                acc[col][3] += oh.w * hv;
            }
        }
    }

    #pragma unroll
    for (int col = 0; col < 4; ++col)
        #pragma unroll
        for (int c = 0; c < 4; ++c)
            lds_s[wave * 4 + col][c][lane] = acc[col][c];
    __syncthreads();

    float m[4];
    #pragma unroll
    for (int col = 0; col < 4; ++col) m[col] = bias[ND + lane];
    for (int c = 0; c < 4; ++c) {
        #pragma unroll 4
        for (int e4 = 0; e4 < 16; ++e4) {
            const float4 M4 = *(const float4*)(&M[c * 4096 + lane * 64 + e4 * 4]);
            #pragma unroll
            for (int col = 0; col < 4; ++col) {
                const float4 s4 = *(const float4*)(&lds_s[wave * 4 + col][c][e4 * 4]);
                m[col] += M4.x * s4.x + M4.y * s4.y + M4.z * s4.z + M4.w * s4.w;
            }
        }
    }
    #pragma unroll
    for (int col = 0; col < 4; ++col)
        out[((size_t)b * NN + i0 + wave * 4 + col) * 128 + ND + lane] = m[col];
}

} // namespace

extern "C" void kernel_launch(void* const* d_in, const int* in_sizes, int n_in,
                              void* d_out, int out_size, void* d_ws, size_t ws_size,
                              hipStream_t stream) {
    (void)in_sizes; (void)n_in; (void)d_ws; (void)ws_size; (void)out_size;
    const float* h    = (const float*)d_in[0];   // [32,1024,64] f32
    const int*   adj  = (const int*)d_in[1];     // [32,1024,1024] i32
    const float* Min  = (const float*)d_in[2];   // [4,64,64] f32
    const float* Mout = (const float*)d_in[3];   // [4,64,64] f32
    const float* bias = (const float*)d_in[4];   // [128] f32
    float* out = (float*)d_out;                  // [32,1024,128] f32

    const dim3 grid(NB * (NN / 16));  // 2048 blocks
    const dim3 block(256);
    ggnn_in <<<grid, block, 0, stream>>>(h, adj, Min,  bias, out);
    ggnn_out<<<grid, block, 0, stream>>>(h, adj, Mout, bias, out);
}

// Round 2
// 276.428 us; speedup vs baseline: 3.8606x; 3.8606x over previous
//
#include <hip/hip_runtime.h>

// GGNN message passing, round 2: bf16 MFMA formulation.
//   For each class c: A_c = (adj==c) in {0,1} (exact in bf16).
//   in : S_c = A_c       @ H ;  m_in  = sum_c S_c @ Min_c^T  + bias[0:64]
//   out: S_c = (adj^T==c)@ H ;  m_out = sum_c S_c @ Mout_c^T + bias[64:128]
// One main kernel, 1024 blocks = 32 b x 16 i-tiles(64 rows) x 2 directions.
// Per 64-j chunk: stage adj tile (rows padded to 68 ints -> 16B-aligned
// ds_read_b128, ~conflict-free) and pre-transposed bf16 H^T chunk (B-frags =
// contiguous-j b128 reads). A-frags built in-register from adj ints (one-hot
// pack, ~12 VALU/class) -> hides under MFMA pipe. Epilogue: S -> LDS (bf16,
// per-wave region, C-layout -> A-layout round-trip) then 32 MFMAs vs M^T.
// Prep kernel fills d_ws: M bf16 [2][4][64][64] (64 KB) + H^T bf16 [32][64][1024] (4 MB).
// HBM floor: adj 2x128 MB + out 16 MB ~= 43 us @ 6.3 TB/s; MFMA ~18 us -> HBM-bound.

namespace {

typedef unsigned short u16;
typedef __attribute__((ext_vector_type(8))) short bf16x8;
typedef __attribute__((ext_vector_type(4))) float f32x4;

constexpr int NB = 32;
constexpr int NN = 1024;
constexpr int ND = 64;

__device__ inline u16 f2bf(float x) {                  // f32 -> bf16 bits, RNE
    unsigned u = __float_as_uint(x);
    return (u16)((u + 0x7FFFu + ((u >> 16) & 1u)) >> 16);
}
__device__ inline unsigned pack2(int a, int b, int c) { // one-hot bf16 pair
    return ((a == c) ? 0x3F80u : 0u) | ((b == c) ? 0x3F800000u : 0u);
}

// prep: blocks 0..511 transpose+convert H -> Hws[b][e][j] bf16;
//       blocks 512..519 convert Min/Mout -> Mws bf16 (row-major [dir][c][d][e]).
__global__ __launch_bounds__(256) void prep(
    const float* __restrict__ h, const float* __restrict__ Min,
    const float* __restrict__ Mout, u16* __restrict__ Mws,
    u16* __restrict__ Hws)
{
    __shared__ u16 hT[64][72];
    const int t = threadIdx.x;
    const int bid = blockIdx.x;
    if (bid < 512) {
        const int b = bid >> 4, j0 = (bid & 15) << 6;
        const float* hb = h + ((size_t)b * NN + j0) * ND;
        #pragma unroll
        for (int k = 0; k < 4; ++k) {
            int idx = t + 256 * k;
            int j = idx >> 4, eq = idx & 15;
            float4 v = *(const float4*)(hb + j * ND + 4 * eq);
            hT[4 * eq + 0][j] = f2bf(v.x);
            hT[4 * eq + 1][j] = f2bf(v.y);
            hT[4 * eq + 2][j] = f2bf(v.z);
            hT[4 * eq + 3][j] = f2bf(v.w);
        }
        __syncthreads();
        #pragma unroll
        for (int k = 0; k < 2; ++k) {
            int idx = t + 256 * k;
            int e = idx >> 3, j8 = idx & 7;
            int4 v = *(const int4*)&hT[e][8 * j8];
            *(int4*)(Hws + ((size_t)b * 64 + e) * NN + j0 + 8 * j8) = v;
        }
    } else {
        const int base = (bid - 512) * 4096;
        #pragma unroll
        for (int k = 0; k < 16; ++k) {
            int idx = base + t + 256 * k;
            float v = (idx < 16384) ? Min[idx] : Mout[idx - 16384];
            Mws[idx] = f2bf(v);
        }
    }
}

__global__ __launch_bounds__(256) void ggnn_main(
    const int* __restrict__ adj, const float* __restrict__ bias,
    const u16* __restrict__ Mws, const u16* __restrict__ Hws,
    float* __restrict__ out)
{
    // LDS: main loop uses adjt[64][68] (17408 B) + hT[64][72] (9216 B);
    // epilogue overlays S as 16 slots (4 waves x 4 classes) of [16][72] bf16.
    __shared__ __align__(16) char smem[36864];
    int (*adjt)[68]     = (int(*)[68])smem;
    u16 (*hT)[72]       = (u16(*)[72])(smem + 17408);
    u16 (*Sb)[16][72]   = (u16(*)[16][72])smem;

    const int t  = threadIdx.x;
    const int w  = t >> 6;          // wave 0..3, owns rows i0+16w..+16
    const int ln = t & 15;          // MFMA lane-low: m / n / col index
    const int qd = (t & 63) >> 4;   // MFMA quad: k-group / row-group
    const bool is_out = blockIdx.x >= 512;
    const int bid2 = blockIdx.x & 511;
    const int b  = bid2 >> 4;
    const int i0 = (bid2 & 15) << 6;

    const int* adjb  = adj + (size_t)b * NN * NN;
    const u16* Hb    = Hws + (size_t)b * 64 * NN;
    const u16* Mbase = Mws + (is_out ? 16384 : 0);
    const int  dofs  = is_out ? 64 : 0;

    f32x4 acc[4][4];                // [class][n-tile], C-layout per wave
    #pragma unroll
    for (int c = 0; c < 4; ++c)
        #pragma unroll
        for (int nt = 0; nt < 4; ++nt) acc[c][nt] = (f32x4){0.f, 0.f, 0.f, 0.f};

    for (int j0 = 0; j0 < NN; j0 += 64) {
        __syncthreads();
        if (!is_out) {
            // adjt[i][j] = adj[b][i0+i][j0+j] (coalesced int4 rows)
            #pragma unroll
            for (int k = 0; k < 4; ++k) {
                int idx = t + 256 * k;
                int i = idx >> 4, j4 = idx & 15;
                int4 v = *(const int4*)(adjb + (size_t)(i0 + i) * NN + j0 + 4 * j4);
                *(int4*)&adjt[i][4 * j4] = v;
            }
        } else {
            // adjt[i][j] = adj[b][j0+j][i0+i] (transpose through LDS)
            #pragma unroll
            for (int k = 0; k < 4; ++k) {
                int idx = t + 256 * k;
                int jj = idx >> 4, i4 = idx & 15;
                int4 v = *(const int4*)(adjb + (size_t)(j0 + jj) * NN + i0 + 4 * i4);
                adjt[4 * i4 + 0][jj] = v.x;
                adjt[4 * i4 + 1][jj] = v.y;
                adjt[4 * i4 + 2][jj] = v.z;
                adjt[4 * i4 + 3][jj] = v.w;
            }
        }
        // hT[e][j] from pre-transposed global H^T (b128 in, b128 out)
        #pragma unroll
        for (int k = 0; k < 2; ++k) {
            int idx = t + 256 * k;
            int e = idx >> 3, j8 = idx & 7;
            int4 v = *(const int4*)(Hb + (size_t)e * NN + j0 + 8 * j8);
            *(int4*)&hT[e][8 * j8] = v;
        }
        __syncthreads();

        #pragma unroll
        for (int ks = 0; ks < 2; ++ks) {
            bf16x8 bf[4];                           // B[k=j][n=e], 4 e-tiles
            #pragma unroll
            for (int nt = 0; nt < 4; ++nt)
                bf[nt] = *(const bf16x8*)&hT[nt * 16 + ln][ks * 32 + qd * 8];
            int4 aA = *(const int4*)&adjt[w * 16 + ln][ks * 32 + qd * 8];
            int4 aB = *(const int4*)&adjt[w * 16 + ln][ks * 32 + qd * 8 + 4];
            #pragma unroll
            for (int c = 0; c < 4; ++c) {
                union { unsigned u[4]; bf16x8 f; } x;
                x.u[0] = pack2(aA.x, aA.y, c);
                x.u[1] = pack2(aA.z, aA.w, c);
                x.u[2] = pack2(aB.x, aB.y, c);
                x.u[3] = pack2(aB.z, aB.w, c);
                #pragma unroll
                for (int nt = 0; nt < 4; ++nt)
                    acc[c][nt] = __builtin_amdgcn_mfma_f32_16x16x32_bf16(
                        x.f, bf[nt], acc[c][nt], 0, 0, 0);
            }
        }
    }

    __syncthreads();   // all waves done reading adjt/hT before S overlays them

    // S_c (C-layout regs) -> LDS bf16 [wave*4+c][i 16][e 72pad]
    #pragma unroll
    for (int c = 0; c < 4; ++c)
        #pragma unroll
        for (int nt = 0; nt < 4; ++nt)
            #pragma unroll
            for (int r = 0; r < 4; ++r)
                Sb[w * 4 + c][qd * 4 + r][nt * 16 + ln] = f2bf(acc[c][nt][r]);

    // m = bias + sum_c S_c @ M_c^T  (A = S from LDS, B = M row-major global)
    f32x4 acc2[4];
    #pragma unroll
    for (int dt = 0; dt < 4; ++dt) {
        float bv = bias[dofs + dt * 16 + ln];
        acc2[dt] = (f32x4){bv, bv, bv, bv};
    }
    #pragma unroll
    for (int c = 0; c < 4; ++c) {
        #pragma unroll
        for (int ks2 = 0; ks2 < 2; ++ks2) {
            bf16x8 af = *(const bf16x8*)&Sb[w * 4 + c][ln][ks2 * 32 + qd * 8];
            #pragma unroll
            for (int dt = 0; dt < 4; ++dt) {
                bf16x8 mf = *(const bf16x8*)(Mbase
                    + (size_t)(c * 64 + dt * 16 + ln) * 64 + ks2 * 32 + qd * 8);
                acc2[dt] = __builtin_amdgcn_mfma_f32_16x16x32_bf16(
                    af, mf, acc2[dt], 0, 0, 0);
            }
        }
    }
    #pragma unroll
    for (int dt = 0; dt < 4; ++dt)
        #pragma unroll
        for (int r = 0; r < 4; ++r)
            out[((size_t)b * NN + i0 + w * 16 + qd * 4 + r) * 128
                + dofs + dt * 16 + ln] = acc2[dt][r];
}

} // namespace

extern "C" void kernel_launch(void* const* d_in, const int* in_sizes, int n_in,
                              void* d_out, int out_size, void* d_ws, size_t ws_size,
                              hipStream_t stream) {
    (void)in_sizes; (void)n_in; (void)out_size; (void)ws_size;
    const float* h    = (const float*)d_in[0];   // [32,1024,64] f32
    const int*   adj  = (const int*)d_in[1];     // [32,1024,1024] i32
    const float* Min  = (const float*)d_in[2];   // [4,64,64] f32
    const float* Mout = (const float*)d_in[3];   // [4,64,64] f32
    const float* bias = (const float*)d_in[4];   // [128] f32
    float* out = (float*)d_out;                  // [32,1024,128] f32

    u16* Mws = (u16*)d_ws;                       // 65536 B
    u16* Hws = (u16*)((char*)d_ws + 65536);      // 4 MB: H^T bf16 [32][64][1024]

    prep<<<520, 256, 0, stream>>>(h, Min, Mout, Mws, Hws);
    ggnn_main<<<1024, 256, 0, stream>>>(adj, bias, Mws, Hws, out);
}

// Round 3
// 262.081 us; speedup vs baseline: 4.0719x; 1.0547x over previous
//
#include <hip/hip_runtime.h>

// GGNN message passing, round 3: 2-bit packed adjacency + 3-plane MFMA.
//
//   adj in {0..3}. Planes: B0 = bit0(adj), B1 = bit1(adj), T = B0&B1.
//   P0 = B0@H, P1 = B1@H, PT = T@H, PA[e] = sum_j h[j][e]  (per batch)
//   m_in  = P0(M1-M0)^T + P1(M2-M0)^T + PT(M0-M1-M2+M3)^T + (bias + PA M0^T)
//   (out-direction: same with adj^T and Mout.)
//
// K1 pack_adj: streams adj (128 MB) once, emits 2-bit row-packs (adjP, 8 MB)
//   and column-packs (adjPT, 8 MB) in main-kernel tile order (4 KB/tile,
//   contiguous, unit-major [u][row] so LDS b128 reads are bank-balanced).
// K2 prep_h: h -> Hws bf16 H^T tiles [b][jc][u(j-octet)][e] (4 MB) + PA (f32).
// K3 prep_m: modified M' (bf16) + base vector (bias + PA M0^T), per dir.
// K4 ggnn_main: 1024 blocks (dir,b,it). Per 256-j chunk: global_load_lds
//   36 KB (adj tile 4 KB + H^T tile 32 KB), then 8 ksteps x {A-unpack ~60
//   VALU, 4 B-frag b128, 12 MFMA}. Epilogue: P->LDS bf16 -> 24 MFMA vs M'.
//
// HBM floor: 128(adj) + 16(packs w) + 16(packs r) + 8(h) + 16(out) ~ 28 us;
// main-kernel compute ~ max(VALU 6.5, LDS 8, MFMA 3) us -> target ~60 us total.

namespace {

typedef unsigned int  u32;
typedef unsigned short u16;
typedef __attribute__((ext_vector_type(8))) short bf16x8;
typedef __attribute__((ext_vector_type(4))) float f32x4;

constexpr int NN = 1024;
constexpr int ND = 64;

__device__ inline u16 f2bf(float x) {                  // f32 -> bf16 bits, RNE
    u32 u = __float_as_uint(x);
    return (u16)((u + 0x7FFFu + ((u >> 16) & 1u)) >> 16);
}
__device__ inline float bf2f(u16 x) { return __uint_as_float(((u32)x) << 16); }

#if defined(__has_builtin)
#if __has_builtin(__builtin_amdgcn_global_load_lds)
#define HAVE_GLL 1
#endif
#endif

__device__ inline void async_copy16(const void* g, void* l) {
    // lane i of the wave copies 16 B from (g + i*16)?? NO: g is per-lane
    // already; HW writes LDS at (uniform l) + lane*16.
#ifdef HAVE_GLL
    typedef __attribute__((address_space(1))) const u32 gu32;
    typedef __attribute__((address_space(3))) u32 lu32;
    __builtin_amdgcn_global_load_lds((gu32*)g, (lu32*)l, 16, 0, 0);
#else
    int lane = threadIdx.x & 63;
    ((uint4*)l)[lane] = *(const uint4*)((const char*)g);
#endif
}

// ---------------------------------------------------------------- K1: pack
// block = (b, It, Jt, s): adj rows It*256 + s*64 .. +64, cols Jt*256 .. +256.
// Emits: adjP[b][jc=Jt][it=It*4+s][u=seg][row]  (row-pack: edges along cols)
//        adjPT[b][jc=It][it=Jt*4+sc][u=s][il]   (col-pack: edges along rows)
__global__ __launch_bounds__(256) void pack_adj(
    const int* __restrict__ adj, u32* __restrict__ adjP, u32* __restrict__ adjPT)
{
    __shared__ u32 rp[64][16];   // [row][16 u32], u32 q = 16 cols
    const int t = threadIdx.x;
    const int bid = blockIdx.x;
    const int b = bid >> 6, It = (bid >> 4) & 3, Jt = (bid >> 2) & 3, s = bid & 3;
    const int* base = adj + ((size_t)b << 20) + (size_t)(It * 256 + s * 64) * NN + Jt * 256;

    const int row = t >> 2, seg = t & 3;
    const int* rptr = base + (size_t)row * NN + seg * 64;
    u32 w[4];
    #pragma unroll
    for (int q = 0; q < 4; ++q) {
        int4 v0 = *(const int4*)(rptr + q * 16 + 0);
        int4 v1 = *(const int4*)(rptr + q * 16 + 4);
        int4 v2 = *(const int4*)(rptr + q * 16 + 8);
        int4 v3 = *(const int4*)(rptr + q * 16 + 12);
        u32 u = (u32)(v0.x & 3) | ((u32)(v0.y & 3) << 2) | ((u32)(v0.z & 3) << 4) | ((u32)(v0.w & 3) << 6)
              | ((u32)(v1.x & 3) << 8) | ((u32)(v1.y & 3) << 10) | ((u32)(v1.z & 3) << 12) | ((u32)(v1.w & 3) << 14)
              | ((u32)(v2.x & 3) << 16) | ((u32)(v2.y & 3) << 18) | ((u32)(v2.z & 3) << 20) | ((u32)(v2.w & 3) << 22)
              | ((u32)(v3.x & 3) << 24) | ((u32)(v3.y & 3) << 26) | ((u32)(v3.z & 3) << 28) | ((u32)(v3.w & 3) << 30);
        w[q] = u;
    }
    // row-pack out: tile (b, jc=Jt, it=It*4+s), unit u=seg, row
    u32* op = adjP + (((((size_t)b * 4 + Jt) * 16 + It * 4 + s) * 4 + seg) * 64 + row) * 4;
    *(uint4*)op = make_uint4(w[0], w[1], w[2], w[3]);
    *(uint4*)&rp[row][seg * 4] = make_uint4(w[0], w[1], w[2], w[3]);
    __syncthreads();

    // col-pack: thread (sc = t>>6, il = t&63)
    const int sc = t >> 6, il = t & 63;
    const int cw = sc * 4 + (il >> 4);
    const int bp = (il & 15) * 2;
    u32 o[4];
    #pragma unroll
    for (int jj = 0; jj < 4; ++jj) {
        u32 acc = 0;
        #pragma unroll
        for (int k = 0; k < 16; ++k)
            acc |= ((rp[jj * 16 + k][cw] >> bp) & 3u) << (2 * k);
        o[jj] = acc;
    }
    u32* op2 = adjPT + (((((size_t)b * 4 + It) * 16 + Jt * 4 + sc) * 4 + s) * 64 + il) * 4;
    *(uint4*)op2 = make_uint4(o[0], o[1], o[2], o[3]);
}

// ---------------------------------------------------------------- K2: prep_h
// block (b, jc): h[b][jc*256..+256][64] f32 -> Hws tile: 2048 units of 16 B,
// unit (u = j-octet 0..31, e 0..63) at linear u*64+e: 8 bf16 = H^T[e][u*8..+8].
// Also accumulates PA[b][e] = sum_j bf16(h[b][j][e]) into f32 via atomics.
__global__ __launch_bounds__(256) void prep_h(
    const float* __restrict__ h, u16* __restrict__ Hws, float* __restrict__ PA)
{
    __shared__ u16 hl[256][72];
    const int t = threadIdx.x;
    const int b = blockIdx.x >> 2, jc = blockIdx.x & 3;
    const float* hb = h + ((size_t)b * NN + jc * 256) * ND;
    #pragma unroll
    for (int k = 0; k < 16; ++k) {
        int j = k * 16 + (t >> 4);
        int e4 = (t & 15) * 4;
        float4 v = *(const float4*)(hb + (size_t)j * ND + e4);
        *(u32*)&hl[j][e4]     = (u32)f2bf(v.x) | ((u32)f2bf(v.y) << 16);
        *(u32*)&hl[j][e4 + 2] = (u32)f2bf(v.z) | ((u32)f2bf(v.w) << 16);
    }
    __syncthreads();
    u16* ob = Hws + (size_t)(b * 4 + jc) * 2048 * 8;
    const int e = t & 63;
    float psum = 0.f;
    #pragma unroll
    for (int k = 0; k < 8; ++k) {
        int u = k * 4 + (t >> 6);
        u32 p0, p1, p2, p3;
        u16 x0 = hl[u * 8 + 0][e], x1 = hl[u * 8 + 1][e], x2 = hl[u * 8 + 2][e], x3 = hl[u * 8 + 3][e];
        u16 x4 = hl[u * 8 + 4][e], x5 = hl[u * 8 + 5][e], x6 = hl[u * 8 + 6][e], x7 = hl[u * 8 + 7][e];
        psum += bf2f(x0) + bf2f(x1) + bf2f(x2) + bf2f(x3) + bf2f(x4) + bf2f(x5) + bf2f(x6) + bf2f(x7);
        p0 = (u32)x0 | ((u32)x1 << 16); p1 = (u32)x2 | ((u32)x3 << 16);
        p2 = (u32)x4 | ((u32)x5 << 16); p3 = (u32)x6 | ((u32)x7 << 16);
        *(uint4*)(ob + (size_t)(u * 64 + e) * 8) = make_uint4(p0, p1, p2, p3);
    }
    atomicAdd(&PA[b * 64 + e], psum);
}

// ---------------------------------------------------------------- K3: prep_m
// Mws[dir][plane][d][e] bf16: plane0 = M1-M0, plane1 = M2-M0, plane2 = M0-M1-M2+M3.
// basews[b][dir][d] = bias[dir*64+d] + sum_e PA[b][e] * M{dir}[0][d][e].
__global__ __launch_bounds__(256) void prep_m(
    const float* __restrict__ Min, const float* __restrict__ Mout,
    const float* __restrict__ bias, const float* __restrict__ PA,
    u16* __restrict__ Mws, float* __restrict__ basews)
{
    const int t = threadIdx.x, bb = blockIdx.x;
    if (bb == 0) {
        for (int i = t; i < 2 * 4096; i += 256) {
            const float* M = (i < 4096) ? Min : Mout;
            int idx = i & 4095;
            float m0 = M[idx], m1 = M[4096 + idx], m2 = M[8192 + idx], m3 = M[12288 + idx];
            u16* o = Mws + (size_t)(i >> 12) * 3 * 4096;
            o[idx]            = f2bf(m1 - m0);
            o[4096 + idx]     = f2bf(m2 - m0);
            o[8192 + idx]     = f2bf(m0 - m1 - m2 + m3);
        }
    }
    if (t < 128) {
        int d = t & 63, dir = t >> 6;
        const float* M0 = (dir ? Mout : Min) + d * 64;
        float s = bias[dir * 64 + d];
        #pragma unroll 8
        for (int e = 0; e < 64; ++e) s += PA[bb * 64 + e] * M0[e];
        basews[(bb * 2 + dir) * 64 + d] = s;
    }
}

// ---------------------------------------------------------------- K4: main
__global__ __launch_bounds__(256, 4) void ggnn_main(
    const u32* __restrict__ adjP, const u32* __restrict__ adjPT,
    const u16* __restrict__ Hws, const u16* __restrict__ Mws,
    const float* __restrict__ basews, float* __restrict__ out)
{
    __shared__ __align__(16) char smem[36864];
    char* adjL = smem;                 // 4 KB: unit (u*64 + row)*16
    char* hL   = smem + 4096;          // 32 KB: unit (u*64 + e)*16
    u16 (*Sb)[16][72] = (u16(*)[16][72])smem;   // epilogue overlay (12 slots)

    const int t = threadIdx.x;
    const int w = t >> 6, lane = t & 63;
    const int ln = t & 15, qd = (t & 63) >> 4, qd2 = qd >> 1;
    const int shamt = (qd & 1) * 16;
    const int bid = blockIdx.x;
    const int dir = bid >> 9;
    const int b = (bid >> 4) & 31, it = bid & 15;

    const u32* Adir = dir ? adjPT : adjP;
    f32x4 acc[3][4];
    #pragma unroll
    for (int p = 0; p < 3; ++p)
        #pragma unroll
        for (int nt = 0; nt < 4; ++nt) acc[p][nt] = (f32x4){0.f, 0.f, 0.f, 0.f};

    for (int jc = 0; jc < 4; ++jc) {
        __syncthreads();
        const char* at = (const char*)(Adir + (size_t)((b * 4 + jc) * 16 + it) * 1024);
        const char* ht = (const char*)(Hws + (size_t)(b * 4 + jc) * 16384);
        if (w == 0) {
            #pragma unroll
            for (int u = 0; u < 4; ++u)
                async_copy16(at + u * 1024 + lane * 16, adjL + u * 1024);
        }
        #pragma unroll
        for (int k = 0; k < 8; ++k) {
            int i = w + k * 4;
            async_copy16(ht + i * 1024 + lane * 16, hL + i * 1024);
        }
        __syncthreads();

        uint4 Ar[4];
        #pragma unroll
        for (int u = 0; u < 4; ++u)
            Ar[u] = *(const uint4*)(adjL + (u * 64 + w * 16 + ln) * 16);

        #pragma unroll
        for (int ks = 0; ks < 8; ++ks) {
            uint4 Q = Ar[ks >> 1];
            u32 a = (ks & 1) ? (qd2 ? Q.w : Q.z) : (qd2 ? Q.y : Q.x);
            u32 f  = (a >> shamt) & 0xFFFFu;
            u32 x0 = f & 0x5555u;
            u32 x1 = (f >> 1) & 0x5555u;
            u32 xt = x0 & x1;
            bf16x8 bf[4];
            #pragma unroll
            for (int nt = 0; nt < 4; ++nt)
                bf[nt] = *(const bf16x8*)(hL + ((ks * 4 + qd) * 64 + nt * 16 + ln) * 16);
            #pragma unroll
            for (int p = 0; p < 3; ++p) {
                u32 xp = (p == 0) ? x0 : (p == 1) ? x1 : xt;
                union { u32 u[4]; bf16x8 v; } A;
                #pragma unroll
                for (int wd = 0; wd < 4; ++wd) {
                    u32 z = xp >> (4 * wd);
                    A.u[wd] = ((z & 1u) | ((z & 4u) << 14)) * 0x3F80u;
                }
                #pragma unroll
                for (int nt = 0; nt < 4; ++nt)
                    acc[p][nt] = __builtin_amdgcn_mfma_f32_16x16x32_bf16(
                        A.v, bf[nt], acc[p][nt], 0, 0, 0);
            }
        }
    }

    __syncthreads();   // all waves done with adjL/hL before Sb overlay

    #pragma unroll
    for (int p = 0; p < 3; ++p)
        #pragma unroll
        for (int nt = 0; nt < 4; ++nt)
            #pragma unroll
            for (int r = 0; r < 4; ++r)
                Sb[w * 3 + p][qd * 4 + r][nt * 16 + ln] = f2bf(acc[p][nt][r]);
    // each wave reads only its own slots -> no barrier needed (lgkmcnt handles)

    const float* bv = basews + (b * 2 + dir) * 64;
    f32x4 acc2[4];
    #pragma unroll
    for (int dt = 0; dt < 4; ++dt) {
        float v = bv[dt * 16 + ln];
        acc2[dt] = (f32x4){v, v, v, v};
    }
    const u16* Mb = Mws + (size_t)dir * 3 * 4096;
    #pragma unroll
    for (int p = 0; p < 3; ++p) {
        #pragma unroll
        for (int ks2 = 0; ks2 < 2; ++ks2) {
            bf16x8 af = *(const bf16x8*)&Sb[w * 3 + p][ln][ks2 * 32 + qd * 8];
            #pragma unroll
            for (int dt = 0; dt < 4; ++dt) {
                bf16x8 mf = *(const bf16x8*)(Mb + (size_t)(p * 64 + dt * 16 + ln) * 64
                                             + ks2 * 32 + qd * 8);
                acc2[dt] = __builtin_amdgcn_mfma_f32_16x16x32_bf16(af, mf, acc2[dt], 0, 0, 0);
            }
        }
    }
    #pragma unroll
    for (int dt = 0; dt < 4; ++dt)
        #pragma unroll
        for (int r = 0; r < 4; ++r)
            out[((size_t)b * NN + it * 64 + w * 16 + qd * 4 + r) * 128
                + dir * 64 + dt * 16 + ln] = acc2[dt][r];
}

} // namespace

extern "C" void kernel_launch(void* const* d_in, const int* in_sizes, int n_in,
                              void* d_out, int out_size, void* d_ws, size_t ws_size,
                              hipStream_t stream) {
    (void)in_sizes; (void)n_in; (void)out_size; (void)ws_size;
    const float* h    = (const float*)d_in[0];   // [32,1024,64] f32
    const int*   adj  = (const int*)d_in[1];     // [32,1024,1024] i32
    const float* Min  = (const float*)d_in[2];   // [4,64,64] f32
    const float* Mout = (const float*)d_in[3];   // [4,64,64] f32
    const float* bias = (const float*)d_in[4];   // [128] f32
    float* out = (float*)d_out;                  // [32,1024,128] f32

    char* ws = (char*)d_ws;
    u32* adjP   = (u32*)(ws + 0);              // 8 MB
    u32* adjPT  = (u32*)(ws + 8388608);        // 8 MB
    u16* Hws    = (u16*)(ws + 16777216);       // 4 MB
    float* PA   = (float*)(ws + 20971520);     // 8 KB
    u16* Mws    = (u16*)(ws + 20979712);       // 48 KB
    float* basews = (float*)(ws + 21028864);   // 16 KB

    hipMemsetAsync(PA, 0, 32 * 64 * sizeof(float), stream);
    pack_adj<<<2048, 256, 0, stream>>>(adj, adjP, adjPT);
    prep_h<<<128, 256, 0, stream>>>(h, Hws, PA);
    prep_m<<<32, 256, 0, stream>>>(Min, Mout, bias, PA, Mws, basews);
    ggnn_main<<<1024, 256, 0, stream>>>(adjP, adjPT, Hws, Mws, basews, out);
}